// Round 5
// baseline (1426.845 us; speedup 1.0000x reference)
//
#include <hip/hip_runtime.h>
#include <stdint.h>

// ---------------------------------------------------------------------------
// TransformerBlock bf16 MFMA. OUTPUT FP32.
// Round 5: revert FFN fusion (round-4 occupancy cliff). All 5 GEMMs now use a
// 256x128x32 tile (32 MFMA per barrier per wave, m97 register regime) with an
// XCD-aware block remap so all n-tiles of one m-tile land on one XCD's L2
// (A-tile fetched once per XCD instead of 8x -> FETCH_SIZE ~5x lower).
// ---------------------------------------------------------------------------

using bf16x8 = __attribute__((ext_vector_type(8))) short;
using f32x4  = __attribute__((ext_vector_type(4))) float;

typedef __attribute__((address_space(3))) uint16_t lds16_t;

__device__ __forceinline__ float bf2f(uint16_t h) {
  union { uint32_t u; float f; } v; v.u = ((uint32_t)h) << 16; return v.f;
}
__device__ __forceinline__ uint16_t f2bf(float f) {
  union { float f; uint32_t u; } v; v.f = f;
  uint32_t r = v.u + 0x7FFFu + ((v.u >> 16) & 1u);
  return (uint16_t)(r >> 16);
}
__device__ __forceinline__ float silu(float x) { return x / (1.0f + __expf(-x)); }

__device__ __forceinline__ void gload16(const uint16_t* g, lds16_t* l) {
  __builtin_amdgcn_global_load_lds(
      (const __attribute__((address_space(1))) void*)g,
      (__attribute__((address_space(3))) void*)l, 16, 0, 0);
}

// ---------------------------------------------------------------------------
// Transpose-cast: wt[n][k] = (bf16) w[k][n].  w is (K,N) fp32 row-major.
// ---------------------------------------------------------------------------
__global__ __launch_bounds__(256)
void transpose_cast(const float* __restrict__ w, uint16_t* __restrict__ wt,
                    int K, int N) {
  __shared__ float tile[32][33];
  int n0 = blockIdx.x * 32, k0 = blockIdx.y * 32;
  int tx = threadIdx.x & 31, ty = threadIdx.x >> 5;
#pragma unroll
  for (int it = 0; it < 4; ++it) {
    int r = ty + it * 8;
    tile[r][tx] = w[(k0 + r) * N + n0 + tx];
  }
  __syncthreads();
#pragma unroll
  for (int it = 0; it < 4; ++it) {
    int r = ty + it * 8;
    wt[(n0 + r) * K + k0 + tx] = f2bf(tile[tx][r]);
  }
}

// ---------------------------------------------------------------------------
// mod = silu(time_emb) @ mod_w + mod_b      (4 x 6144, K=1024)
// ---------------------------------------------------------------------------
__global__ __launch_bounds__(1024)
void mod_kernel(const float* __restrict__ te, const float* __restrict__ mw,
                const float* __restrict__ mb, float* __restrict__ mod) {
  __shared__ float ste[4096];
  __shared__ float red[4][4][256];
  int tid = threadIdx.x;
  for (int i = tid; i < 4096; i += 1024) { float v = te[i]; ste[i] = silu(v); }
  __syncthreads();
  int kslice = tid >> 8, cl = tid & 255;
  int col = blockIdx.x * 256 + cl;
  float acc[4] = {0.f, 0.f, 0.f, 0.f};
  for (int kk = 0; kk < 256; ++kk) {
    int k = kslice * 256 + kk;
    float wv = mw[k * 6144 + col];
#pragma unroll
    for (int b = 0; b < 4; ++b) acc[b] += ste[b * 1024 + k] * wv;
  }
#pragma unroll
  for (int b = 0; b < 4; ++b) red[kslice][b][cl] = acc[b];
  __syncthreads();
  if (kslice == 0) {
#pragma unroll
    for (int b = 0; b < 4; ++b)
      mod[b * 6144 + col] =
          red[0][b][cl] + red[1][b][cl] + red[2][b][cl] + red[3][b][cl] + mb[col];
  }
}

// ---------------------------------------------------------------------------
// RMSNorm + modulation -> bf16.  One block per row.
// ---------------------------------------------------------------------------
__global__ __launch_bounds__(256)
void norm_kernel(const float* __restrict__ xf,
                 const float* __restrict__ w, const float* __restrict__ mod,
                 int shift_off, int scale_off, uint16_t* __restrict__ out) {
  int row = blockIdx.x;
  int b = row >> 12;
  int tid = threadIdx.x;
  float4 t = *(const float4*)(xf + (size_t)row * 1024 + tid * 4);
  float v[4] = {t.x, t.y, t.z, t.w};
  float ss = v[0] * v[0] + v[1] * v[1] + v[2] * v[2] + v[3] * v[3];
#pragma unroll
  for (int off = 1; off < 64; off <<= 1) ss += __shfl_xor(ss, off);
  __shared__ float red[4];
  if ((tid & 63) == 0) red[tid >> 6] = ss;
  __syncthreads();
  float tot = red[0] + red[1] + red[2] + red[3];
  float rinv = rsqrtf(tot * (1.0f / 1024.0f) + 1e-6f);
  const float* mrow = mod + b * 6144;
  uint16_t o[4];
#pragma unroll
  for (int c = 0; c < 4; ++c) {
    int col = tid * 4 + c;
    float hv = v[c] * rinv * w[col] * (1.0f + mrow[scale_off + col]) + mrow[shift_off + col];
    o[c] = f2bf(hv);
  }
  uint2 pk;
  pk.x = (uint32_t)o[0] | ((uint32_t)o[1] << 16);
  pk.y = (uint32_t)o[2] | ((uint32_t)o[3] << 16);
  *(uint2*)(out + (size_t)row * 1024 + tid * 4) = pk;
}

// ---------------------------------------------------------------------------
// GEMM: C(M,N) = A(M,K) @ Bt(N,K), 256x128x32 tile, 4 waves (2x2), each wave
// 128x64 via 8x4 tiles of mfma_16x16x32_bf16 (32 MFMA per barrier-pair).
// XCD remap: bid&7 = XCD; all tiles_n blocks of one tm on one XCD.
// Staging via global_load_lds w=16, BK=32 rows (4 chunks of 16B), XOR swizzle
// phys p of row r holds logical p^(r&3); frag read offset (quad^(col&3))<<3.
// MODE: 0 store bf16 | 1 x+gate1*C -> fp32 | 2 silu bf16 | 3 h1*C bf16
//       4 xio += gate2*C (fp32 RMW)
// Requires M % 256 == 0 and (M/256) % 8 == 0.
// ---------------------------------------------------------------------------
template <int MODE>
__global__ __launch_bounds__(256)
void gemm_bt(const uint16_t* __restrict__ A, const uint16_t* __restrict__ Bt,
             int M, int N, int K,
             uint16_t* __restrict__ obf,
             const float* __restrict__ xin, const float* __restrict__ mod,
             const uint16_t* __restrict__ h1, float* __restrict__ xio) {
  __shared__ uint16_t As[256 * 32];   // 16 KB
  __shared__ uint16_t Bs[128 * 32];   //  8 KB
  const int tiles_n = (N + 127) >> 7;
  const int xcd = blockIdx.x & 7;
  const int slot = blockIdx.x >> 3;
  const int tm = (slot / tiles_n) * 8 + xcd;
  const int tn = slot % tiles_n;
  const int m0 = tm * 256, n0 = tn * 128;
  const int tid = threadIdx.x;
  const int wave = tid >> 6, lane = tid & 63;
  const int wrow = (wave & 1) * 128, wcol = (wave >> 1) * 64;
  const int col = lane & 15, quad = lane >> 4;

  // staging: thread t covers (row = t>>2 + 64k, phys chunk = t&3)
  const int srow = tid >> 2, sphys = tid & 3;
  const int slog = ((sphys ^ (srow & 3)) << 3);   // source elem offset in row
  const uint16_t* Ag[4]; lds16_t* Al[4];
#pragma unroll
  for (int k = 0; k < 4; ++k) {
    Ag[k] = A + (size_t)(m0 + srow + 64 * k) * K + slog;
    Al[k] = (lds16_t*)As + (tid + 256 * k) * 8;
  }
  const uint16_t* Bg[2]; lds16_t* Bl[2];
#pragma unroll
  for (int k = 0; k < 2; ++k) {
    int br = n0 + srow + 64 * k; if (br >= N) br = N - 1;
    Bg[k] = Bt + (size_t)br * K + slog;
    Bl[k] = (lds16_t*)Bs + (tid + 256 * k) * 8;
  }

  f32x4 acc[8][4];
#pragma unroll
  for (int i = 0; i < 8; ++i)
#pragma unroll
    for (int j = 0; j < 4; ++j) acc[i][j] = (f32x4){0.f, 0.f, 0.f, 0.f};

  const int swz = (quad ^ (col & 3)) << 3;

  for (int k0 = 0; k0 < K; k0 += 32) {
    __syncthreads();
#pragma unroll
    for (int k = 0; k < 4; ++k) gload16(Ag[k] + k0, Al[k]);
#pragma unroll
    for (int k = 0; k < 2; ++k) gload16(Bg[k] + k0, Bl[k]);
    __syncthreads();
    bf16x8 af[8], bfr[4];
#pragma unroll
    for (int j = 0; j < 4; ++j)
      bfr[j] = *(const bf16x8*)(Bs + (wcol + j * 16 + col) * 32 + swz);
#pragma unroll
    for (int i = 0; i < 8; ++i)
      af[i] = *(const bf16x8*)(As + (wrow + i * 16 + col) * 32 + swz);
#pragma unroll
    for (int i = 0; i < 8; ++i)
#pragma unroll
      for (int j = 0; j < 4; ++j)
        acc[i][j] = __builtin_amdgcn_mfma_f32_16x16x32_bf16(af[i], bfr[j], acc[i][j], 0, 0, 0);
  }

#pragma unroll
  for (int i = 0; i < 8; ++i) {
#pragma unroll
    for (int j = 0; j < 4; ++j) {
#pragma unroll
      for (int r = 0; r < 4; ++r) {
        int row = m0 + wrow + i * 16 + quad * 4 + r;
        int cn = n0 + wcol + j * 16 + col;
        if (cn >= N) continue;
        float c = acc[i][j][r];
        if (MODE == 0) {
          obf[(size_t)row * N + cn] = f2bf(c);
        } else if (MODE == 1) {
          int b = row >> 12;
          size_t idx = (size_t)row * 1024 + cn;
          float g = mod[b * 6144 + 2048 + cn];
          xio[idx] = xin[idx] + g * c;
        } else if (MODE == 2) {
          obf[(size_t)row * N + cn] = f2bf(silu(c));
        } else if (MODE == 3) {
          size_t idx = (size_t)row * N + cn;
          obf[idx] = f2bf(bf2f(h1[idx]) * c);
        } else {  // MODE 4
          int b = row >> 12;
          size_t idx = (size_t)row * 1024 + cn;
          float g = mod[b * 6144 + 5120 + cn];
          xio[idx] = xio[idx] + g * c;
        }
      }
    }
  }
}

// ---------------------------------------------------------------------------
// Fused attention (unchanged, verified).
// ---------------------------------------------------------------------------
__global__ __launch_bounds__(256)
void attn_kernel(const uint16_t* __restrict__ qkv, uint16_t* __restrict__ out) {
  __shared__ uint16_t lds[32768];
  const int tid = threadIdx.x;
  const int bid = blockIdx.x;
  const int slice = bid >> 2, qc = bid & 3;
  const int bt = slice >> 4, h = slice & 15;
  const int row0 = bt * 256;
  const int wave = tid >> 6, lane = tid & 63;
  const int col = lane & 15, quad = lane >> 4;

  {
    int kr = tid;
    const uint16_t* kp = qkv + (size_t)(row0 + kr) * 3072 + 1024 + h * 64;
    uint16_t* ks = lds + kr * 64;
#pragma unroll
    for (int kc = 0; kc < 8; ++kc) {
      uint4 v = *(const uint4*)(kp + kc * 8);
      *(uint4*)(ks + ((kc ^ (kr & 7)) << 3)) = v;
    }
  }
  {
    int p = tid & 127, dh = tid >> 7;
    const uint16_t* vp0 = qkv + (size_t)(row0 + 2 * p) * 3072 + 2048 + h * 64 + dh * 32;
    const uint16_t* vp1 = vp0 + 3072;
    uint16_t r0[32], r1[32];
#pragma unroll
    for (int i = 0; i < 4; ++i) {
      *(uint4*)(r0 + i * 8) = *(const uint4*)(vp0 + i * 8);
      *(uint4*)(r1 + i * 8) = *(const uint4*)(vp1 + i * 8);
    }
    uint32_t* vt = (uint32_t*)(lds + 16384);
    int krc = p >> 2;
#pragma unroll
    for (int i = 0; i < 32; ++i) {
      int d = dh * 32 + i;
      uint32_t val = (uint32_t)r0[i] | ((uint32_t)r1[i] << 16);
      vt[d * 128 + ((krc ^ (d & 7)) << 2) + (p & 3)] = val;
    }
  }
  __syncthreads();

  const int qrow = qc * 64 + wave * 16 + col;
  const uint16_t* qp = qkv + (size_t)(row0 + qrow) * 3072 + h * 64;
  bf16x8 aq0 = *(const bf16x8*)(qp + quad * 8);
  bf16x8 aq1 = *(const bf16x8*)(qp + 32 + quad * 8);

  f32x4 sc[16];
#pragma unroll
  for (int t = 0; t < 16; ++t) {
    int n = t * 16 + col;
    const uint16_t* kb = lds + n * 64;
    bf16x8 b0 = *(const bf16x8*)(kb + ((quad ^ (n & 7)) << 3));
    bf16x8 b1 = *(const bf16x8*)(kb + (((4 + quad) ^ (n & 7)) << 3));
    f32x4 s = (f32x4){0.f, 0.f, 0.f, 0.f};
    s = __builtin_amdgcn_mfma_f32_16x16x32_bf16(aq0, b0, s, 0, 0, 0);
    s = __builtin_amdgcn_mfma_f32_16x16x32_bf16(aq1, b1, s, 0, 0, 0);
    sc[t] = s;
  }

  const float scale = 0.125f;
  float inv[4];
#pragma unroll
  for (int i = 0; i < 4; ++i) {
    float m = -1e30f;
#pragma unroll
    for (int t = 0; t < 16; ++t) m = fmaxf(m, sc[t][i]);
    m = fmaxf(m, __shfl_xor(m, 1));
    m = fmaxf(m, __shfl_xor(m, 2));
    m = fmaxf(m, __shfl_xor(m, 4));
    m = fmaxf(m, __shfl_xor(m, 8));
    m *= scale;
    float sum = 0.f;
#pragma unroll
    for (int t = 0; t < 16; ++t) {
      float p = __expf(sc[t][i] * scale - m);
      sc[t][i] = p;
      sum += p;
    }
    sum += __shfl_xor(sum, 1);
    sum += __shfl_xor(sum, 2);
    sum += __shfl_xor(sum, 4);
    sum += __shfl_xor(sum, 8);
    inv[i] = 1.0f / sum;
  }
  __syncthreads();

  uint16_t* P = lds + wave * 4096;
#pragma unroll
  for (int t = 0; t < 16; ++t) {
    int pcb = t * 2 + (col >> 3);
#pragma unroll
    for (int i = 0; i < 4; ++i) {
      int r = quad * 4 + i;
      P[r * 256 + ((pcb ^ (r & 7)) << 3) + (col & 7)] = f2bf(sc[t][i] * inv[i]);
    }
  }

  f32x4 o[4];
#pragma unroll
  for (int nt = 0; nt < 4; ++nt) o[nt] = (f32x4){0.f, 0.f, 0.f, 0.f};
  const uint16_t* Vt = lds + 16384;
#pragma unroll
  for (int c = 0; c < 8; ++c) {
    int pc = c * 4 + quad;
    bf16x8 ap = *(const bf16x8*)(P + col * 256 + ((pc ^ (col & 7)) << 3));
#pragma unroll
    for (int nt = 0; nt < 4; ++nt) {
      int d = nt * 16 + col;
      bf16x8 bv = *(const bf16x8*)(Vt + d * 256 + ((pc ^ (d & 7)) << 3));
      o[nt] = __builtin_amdgcn_mfma_f32_16x16x32_bf16(ap, bv, o[nt], 0, 0, 0);
    }
  }

#pragma unroll
  for (int nt = 0; nt < 4; ++nt) {
#pragma unroll
    for (int r = 0; r < 4; ++r) {
      int grow = row0 + qc * 64 + wave * 16 + quad * 4 + r;
      int gcol = h * 64 + nt * 16 + col;
      out[(size_t)grow * 1024 + gcol] = f2bf(o[nt][r]);
    }
  }
}

// ---------------------------------------------------------------------------
extern "C" void kernel_launch(void* const* d_in, const int* in_sizes, int n_in,
                              void* d_out, int out_size, void* d_ws, size_t ws_size,
                              hipStream_t stream) {
  const float* x        = (const float*)d_in[0];
  const float* time_emb = (const float*)d_in[1];
  const float* norm1_w  = (const float*)d_in[2];
  const float* norm2_w  = (const float*)d_in[3];
  const float* qkv_w    = (const float*)d_in[4];
  const float* out_w    = (const float*)d_in[5];
  const float* w1       = (const float*)d_in[6];
  const float* w2       = (const float*)d_in[7];
  const float* w3       = (const float*)d_in[8];
  const float* mod_w    = (const float*)d_in[9];
  const float* mod_b    = (const float*)d_in[10];
  float* out = (float*)d_out;

  char* ws = (char*)d_ws;
  float*    mod    = (float*)(ws);
  uint16_t* wqkv_t = (uint16_t*)(ws + 98304);
  uint16_t* wout_t = (uint16_t*)(ws + 6389760);
  uint16_t* w1t    = (uint16_t*)(ws + 8486912);
  uint16_t* w2t    = (uint16_t*)(ws + 14123008);
  uint16_t* w3t    = (uint16_t*)(ws + 19759104);
  uint16_t* hbuf   = (uint16_t*)(ws + 25395200);
  uint16_t* qkvb   = (uint16_t*)(ws + 58949632);
  uint16_t* hid    = qkvb;

  dim3 blk(256);
  transpose_cast<<<dim3(3072 / 32, 1024 / 32), blk, 0, stream>>>(qkv_w, wqkv_t, 1024, 3072);
  transpose_cast<<<dim3(1024 / 32, 1024 / 32), blk, 0, stream>>>(out_w, wout_t, 1024, 1024);
  transpose_cast<<<dim3(2752 / 32, 1024 / 32), blk, 0, stream>>>(w1, w1t, 1024, 2752);
  transpose_cast<<<dim3(2752 / 32, 1024 / 32), blk, 0, stream>>>(w2, w2t, 1024, 2752);
  transpose_cast<<<dim3(1024 / 32, 2752 / 32), blk, 0, stream>>>(w3, w3t, 2752, 1024);

  mod_kernel<<<24, 1024, 0, stream>>>(time_emb, mod_w, mod_b, mod);

  norm_kernel<<<16384, blk, 0, stream>>>(x, norm1_w, mod, 0, 1024, hbuf);

  // qkv = h @ qkv_w   (M=16384,N=3072,K=1024)  grid = 64 m-tiles * 24 n-tiles
  gemm_bt<0><<<64 * 24, blk, 0, stream>>>(hbuf, wqkv_t, 16384, 3072, 1024,
                                          qkvb, nullptr, nullptr, nullptr, nullptr);
  attn_kernel<<<4096, blk, 0, stream>>>(qkvb, hbuf);

  // x1 = x + gate1 * (attn @ out_w) -> d_out (fp32)
  gemm_bt<1><<<64 * 8, blk, 0, stream>>>(hbuf, wout_t, 16384, 1024, 1024,
                                         nullptr, x, mod, nullptr, out);
  // h2 = rmsnorm(x1)*(1+scale2)+shift2
  norm_kernel<<<16384, blk, 0, stream>>>(out, norm2_w, mod, 3072, 4096, hbuf);

  // h1 = silu(h2 @ w1)  (N=2752)
  gemm_bt<2><<<64 * 22, blk, 0, stream>>>(hbuf, w1t, 16384, 2752, 1024,
                                          hid, nullptr, nullptr, nullptr, nullptr);
  // hid = h1 * (h2 @ w2)   (in place over h1)
  gemm_bt<3><<<64 * 22, blk, 0, stream>>>(hbuf, w2t, 16384, 2752, 1024,
                                          hid, nullptr, nullptr, hid, nullptr);
  // out = x1 + gate2 * (hid @ w3)   (fp32 RMW, K=2752)
  gemm_bt<4><<<64 * 8, blk, 0, stream>>>(hid, w3t, 16384, 1024, 2752,
                                         nullptr, nullptr, mod, nullptr, out);
}

// Round 6
// 911.330 us; speedup vs baseline: 1.5657x; 1.5657x over previous
//
#include <hip/hip_runtime.h>
#include <stdint.h>

// ---------------------------------------------------------------------------
// TransformerBlock bf16 MFMA. OUTPUT FP32.
// Round 6: round-3 GEMM structure (128x128x32, 64 acc VGPR — the proven
// register sweet spot) + double-buffered LDS staging (loads for tile k+1 in
// flight during compute of tile k; one barrier/iter) + XCD-aware remap
// (tm-major per XCD; round 5 proved it halves FETCH_SIZE).
// ---------------------------------------------------------------------------

using bf16x8 = __attribute__((ext_vector_type(8))) short;
using f32x4  = __attribute__((ext_vector_type(4))) float;

typedef __attribute__((address_space(3))) uint16_t lds16_t;

__device__ __forceinline__ float bf2f(uint16_t h) {
  union { uint32_t u; float f; } v; v.u = ((uint32_t)h) << 16; return v.f;
}
__device__ __forceinline__ uint16_t f2bf(float f) {
  union { float f; uint32_t u; } v; v.f = f;
  uint32_t r = v.u + 0x7FFFu + ((v.u >> 16) & 1u);
  return (uint16_t)(r >> 16);
}
__device__ __forceinline__ float silu(float x) { return x / (1.0f + __expf(-x)); }

__device__ __forceinline__ void gload16(const uint16_t* g, lds16_t* l) {
  __builtin_amdgcn_global_load_lds(
      (const __attribute__((address_space(1))) void*)g,
      (__attribute__((address_space(3))) void*)l, 16, 0, 0);
}

// ---------------------------------------------------------------------------
// Transpose-cast: wt[n][k] = (bf16) w[k][n].  w is (K,N) fp32 row-major.
// ---------------------------------------------------------------------------
__global__ __launch_bounds__(256)
void transpose_cast(const float* __restrict__ w, uint16_t* __restrict__ wt,
                    int K, int N) {
  __shared__ float tile[32][33];
  int n0 = blockIdx.x * 32, k0 = blockIdx.y * 32;
  int tx = threadIdx.x & 31, ty = threadIdx.x >> 5;
#pragma unroll
  for (int it = 0; it < 4; ++it) {
    int r = ty + it * 8;
    tile[r][tx] = w[(k0 + r) * N + n0 + tx];
  }
  __syncthreads();
#pragma unroll
  for (int it = 0; it < 4; ++it) {
    int r = ty + it * 8;
    wt[(n0 + r) * K + k0 + tx] = f2bf(tile[tx][r]);
  }
}

// ---------------------------------------------------------------------------
// mod = silu(time_emb) @ mod_w + mod_b      (4 x 6144, K=1024)
// ---------------------------------------------------------------------------
__global__ __launch_bounds__(1024)
void mod_kernel(const float* __restrict__ te, const float* __restrict__ mw,
                const float* __restrict__ mb, float* __restrict__ mod) {
  __shared__ float ste[4096];
  __shared__ float red[4][4][256];
  int tid = threadIdx.x;
  for (int i = tid; i < 4096; i += 1024) { float v = te[i]; ste[i] = silu(v); }
  __syncthreads();
  int kslice = tid >> 8, cl = tid & 255;
  int col = blockIdx.x * 256 + cl;
  float acc[4] = {0.f, 0.f, 0.f, 0.f};
  for (int kk = 0; kk < 256; ++kk) {
    int k = kslice * 256 + kk;
    float wv = mw[k * 6144 + col];
#pragma unroll
    for (int b = 0; b < 4; ++b) acc[b] += ste[b * 1024 + k] * wv;
  }
#pragma unroll
  for (int b = 0; b < 4; ++b) red[kslice][b][cl] = acc[b];
  __syncthreads();
  if (kslice == 0) {
#pragma unroll
    for (int b = 0; b < 4; ++b)
      mod[b * 6144 + col] =
          red[0][b][cl] + red[1][b][cl] + red[2][b][cl] + red[3][b][cl] + mb[col];
  }
}

// ---------------------------------------------------------------------------
// RMSNorm + modulation -> bf16.  One block per row.
// ---------------------------------------------------------------------------
__global__ __launch_bounds__(256)
void norm_kernel(const float* __restrict__ xf,
                 const float* __restrict__ w, const float* __restrict__ mod,
                 int shift_off, int scale_off, uint16_t* __restrict__ out) {
  int row = blockIdx.x;
  int b = row >> 12;
  int tid = threadIdx.x;
  float4 t = *(const float4*)(xf + (size_t)row * 1024 + tid * 4);
  float v[4] = {t.x, t.y, t.z, t.w};
  float ss = v[0] * v[0] + v[1] * v[1] + v[2] * v[2] + v[3] * v[3];
#pragma unroll
  for (int off = 1; off < 64; off <<= 1) ss += __shfl_xor(ss, off);
  __shared__ float red[4];
  if ((tid & 63) == 0) red[tid >> 6] = ss;
  __syncthreads();
  float tot = red[0] + red[1] + red[2] + red[3];
  float rinv = rsqrtf(tot * (1.0f / 1024.0f) + 1e-6f);
  const float* mrow = mod + b * 6144;
  uint16_t o[4];
#pragma unroll
  for (int c = 0; c < 4; ++c) {
    int col = tid * 4 + c;
    float hv = v[c] * rinv * w[col] * (1.0f + mrow[scale_off + col]) + mrow[shift_off + col];
    o[c] = f2bf(hv);
  }
  uint2 pk;
  pk.x = (uint32_t)o[0] | ((uint32_t)o[1] << 16);
  pk.y = (uint32_t)o[2] | ((uint32_t)o[3] << 16);
  *(uint2*)(out + (size_t)row * 1024 + tid * 4) = pk;
}

// ---------------------------------------------------------------------------
// GEMM: C(M,N) = A(M,K)bf16 @ Bt(N,K)bf16, 128x128x32 tile, 4 waves (2x2),
// wave = 64x64 via 4x4 mfma_16x16x32_bf16. Double-buffered global_load_lds
// staging (loads for k+1 in flight during compute of k; 1 barrier/iter).
// XCD remap: xcd = bid&7; tm-major per XCD (A-tile hot in that XCD's L2).
// Requires (M/128) % 8 == 0.
// MODE: 0 store bf16 | 1 x+gate1*C -> fp32 | 2 silu bf16 | 3 h1*C bf16
//       4 xio += gate2*C (fp32 RMW)
// ---------------------------------------------------------------------------
template <int MODE>
__global__ __launch_bounds__(256)
void gemm_bt(const uint16_t* __restrict__ A, const uint16_t* __restrict__ Bt,
             int M, int N, int K,
             uint16_t* __restrict__ obf,
             const float* __restrict__ xin, const float* __restrict__ mod,
             const uint16_t* __restrict__ h1, float* __restrict__ xio) {
  __shared__ uint16_t As[2][128 * 32];   // 2 x 8 KB
  __shared__ uint16_t Bs[2][128 * 32];
  const int tiles_n = (N + 127) >> 7;
  const int xcd = blockIdx.x & 7;
  const int slot = blockIdx.x >> 3;
  const int tm = (slot / tiles_n) * 8 + xcd;
  const int tn = slot % tiles_n;
  const int m0 = tm * 128, n0 = tn * 128;
  const int tid = threadIdx.x;
  const int wave = tid >> 6, lane = tid & 63;
  const int wm = (wave & 1) * 64, wn = (wave >> 1) * 64;
  const int col = lane & 15, quad = lane >> 4;

  // staging: lane covers (row = wave*32 + (lane>>2) [+16], phys chunk lane&3)
  // source logical chunk = (lane&3) ^ (row&3)  (XOR swizzle applied at source)
  const int lrow = lane >> 2, lchk = lane & 3;
  const int schunk = ((lchk ^ (lrow & 3)) << 3);
  const uint16_t* Ag0 = A + (size_t)(m0 + wave * 32 + lrow) * K + schunk;
  const uint16_t* Ag1 = Ag0 + (size_t)16 * K;
  int br0 = n0 + wave * 32 + lrow;      if (br0 >= N) br0 = N - 1;
  int br1 = n0 + wave * 32 + 16 + lrow; if (br1 >= N) br1 = N - 1;
  const uint16_t* Bg0 = Bt + (size_t)br0 * K + schunk;
  const uint16_t* Bg1 = Bt + (size_t)br1 * K + schunk;
  lds16_t* Aw0[2]; lds16_t* Aw1[2]; lds16_t* Bw0[2]; lds16_t* Bw1[2];
#pragma unroll
  for (int b = 0; b < 2; ++b) {
    Aw0[b] = (lds16_t*)As[b] + wave * 1024;
    Aw1[b] = Aw0[b] + 512;
    Bw0[b] = (lds16_t*)Bs[b] + wave * 1024;
    Bw1[b] = Bw0[b] + 512;
  }

  f32x4 acc[4][4];
#pragma unroll
  for (int i = 0; i < 4; ++i)
#pragma unroll
    for (int j = 0; j < 4; ++j) acc[i][j] = (f32x4){0.f, 0.f, 0.f, 0.f};

  const int swz = (quad ^ (col & 3)) << 3;

  // prologue: stage tile 0 into buffer 0
  gload16(Ag0, Aw0[0]);
  gload16(Ag1, Aw1[0]);
  gload16(Bg0, Bw0[0]);
  gload16(Bg1, Bw1[0]);

  for (int k0 = 0; k0 < K; k0 += 32) {
    const int cur = (k0 >> 5) & 1;
    __syncthreads();   // drains vmcnt: buffer `cur` staged; prev reads done
    if (k0 + 32 < K) { // issue next tile into the other buffer (in flight
      const int kn = k0 + 32;             // during this iteration's compute)
      gload16(Ag0 + kn, Aw0[cur ^ 1]);
      gload16(Ag1 + kn, Aw1[cur ^ 1]);
      gload16(Bg0 + kn, Bw0[cur ^ 1]);
      gload16(Bg1 + kn, Bw1[cur ^ 1]);
    }
    const uint16_t* Ab = As[cur];
    const uint16_t* Bb = Bs[cur];
    bf16x8 af[4], bfr[4];
#pragma unroll
    for (int i = 0; i < 4; ++i)
      af[i] = *(const bf16x8*)(Ab + (wm + i * 16 + col) * 32 + swz);
#pragma unroll
    for (int j = 0; j < 4; ++j)
      bfr[j] = *(const bf16x8*)(Bb + (wn + j * 16 + col) * 32 + swz);
#pragma unroll
    for (int i = 0; i < 4; ++i)
#pragma unroll
      for (int j = 0; j < 4; ++j)
        acc[i][j] = __builtin_amdgcn_mfma_f32_16x16x32_bf16(af[i], bfr[j], acc[i][j], 0, 0, 0);
  }

#pragma unroll
  for (int i = 0; i < 4; ++i) {
#pragma unroll
    for (int j = 0; j < 4; ++j) {
#pragma unroll
      for (int r = 0; r < 4; ++r) {
        int row = m0 + wm + i * 16 + quad * 4 + r;
        int cn = n0 + wn + j * 16 + col;
        if (cn >= N) continue;
        float c = acc[i][j][r];
        if (MODE == 0) {
          obf[(size_t)row * N + cn] = f2bf(c);
        } else if (MODE == 1) {
          int b = row >> 12;
          size_t idx = (size_t)row * 1024 + cn;
          float g = mod[b * 6144 + 2048 + cn];
          xio[idx] = xin[idx] + g * c;
        } else if (MODE == 2) {
          obf[(size_t)row * N + cn] = f2bf(silu(c));
        } else if (MODE == 3) {
          size_t idx = (size_t)row * N + cn;
          obf[idx] = f2bf(bf2f(h1[idx]) * c);
        } else {  // MODE 4
          int b = row >> 12;
          size_t idx = (size_t)row * 1024 + cn;
          float g = mod[b * 6144 + 5120 + cn];
          xio[idx] = xio[idx] + g * c;
        }
      }
    }
  }
}

// ---------------------------------------------------------------------------
// Fused attention (unchanged, verified).
// ---------------------------------------------------------------------------
__global__ __launch_bounds__(256)
void attn_kernel(const uint16_t* __restrict__ qkv, uint16_t* __restrict__ out) {
  __shared__ uint16_t lds[32768];
  const int tid = threadIdx.x;
  const int bid = blockIdx.x;
  const int slice = bid >> 2, qc = bid & 3;
  const int bt = slice >> 4, h = slice & 15;
  const int row0 = bt * 256;
  const int wave = tid >> 6, lane = tid & 63;
  const int col = lane & 15, quad = lane >> 4;

  {
    int kr = tid;
    const uint16_t* kp = qkv + (size_t)(row0 + kr) * 3072 + 1024 + h * 64;
    uint16_t* ks = lds + kr * 64;
#pragma unroll
    for (int kc = 0; kc < 8; ++kc) {
      uint4 v = *(const uint4*)(kp + kc * 8);
      *(uint4*)(ks + ((kc ^ (kr & 7)) << 3)) = v;
    }
  }
  {
    int p = tid & 127, dh = tid >> 7;
    const uint16_t* vp0 = qkv + (size_t)(row0 + 2 * p) * 3072 + 2048 + h * 64 + dh * 32;
    const uint16_t* vp1 = vp0 + 3072;
    uint16_t r0[32], r1[32];
#pragma unroll
    for (int i = 0; i < 4; ++i) {
      *(uint4*)(r0 + i * 8) = *(const uint4*)(vp0 + i * 8);
      *(uint4*)(r1 + i * 8) = *(const uint4*)(vp1 + i * 8);
    }
    uint32_t* vt = (uint32_t*)(lds + 16384);
    int krc = p >> 2;
#pragma unroll
    for (int i = 0; i < 32; ++i) {
      int d = dh * 32 + i;
      uint32_t val = (uint32_t)r0[i] | ((uint32_t)r1[i] << 16);
      vt[d * 128 + ((krc ^ (d & 7)) << 2) + (p & 3)] = val;
    }
  }
  __syncthreads();

  const int qrow = qc * 64 + wave * 16 + col;
  const uint16_t* qp = qkv + (size_t)(row0 + qrow) * 3072 + h * 64;
  bf16x8 aq0 = *(const bf16x8*)(qp + quad * 8);
  bf16x8 aq1 = *(const bf16x8*)(qp + 32 + quad * 8);

  f32x4 sc[16];
#pragma unroll
  for (int t = 0; t < 16; ++t) {
    int n = t * 16 + col;
    const uint16_t* kb = lds + n * 64;
    bf16x8 b0 = *(const bf16x8*)(kb + ((quad ^ (n & 7)) << 3));
    bf16x8 b1 = *(const bf16x8*)(kb + (((4 + quad) ^ (n & 7)) << 3));
    f32x4 s = (f32x4){0.f, 0.f, 0.f, 0.f};
    s = __builtin_amdgcn_mfma_f32_16x16x32_bf16(aq0, b0, s, 0, 0, 0);
    s = __builtin_amdgcn_mfma_f32_16x16x32_bf16(aq1, b1, s, 0, 0, 0);
    sc[t] = s;
  }

  const float scale = 0.125f;
  float inv[4];
#pragma unroll
  for (int i = 0; i < 4; ++i) {
    float m = -1e30f;
#pragma unroll
    for (int t = 0; t < 16; ++t) m = fmaxf(m, sc[t][i]);
    m = fmaxf(m, __shfl_xor(m, 1));
    m = fmaxf(m, __shfl_xor(m, 2));
    m = fmaxf(m, __shfl_xor(m, 4));
    m = fmaxf(m, __shfl_xor(m, 8));
    m *= scale;
    float sum = 0.f;
#pragma unroll
    for (int t = 0; t < 16; ++t) {
      float p = __expf(sc[t][i] * scale - m);
      sc[t][i] = p;
      sum += p;
    }
    sum += __shfl_xor(sum, 1);
    sum += __shfl_xor(sum, 2);
    sum += __shfl_xor(sum, 4);
    sum += __shfl_xor(sum, 8);
    inv[i] = 1.0f / sum;
  }
  __syncthreads();

  uint16_t* P = lds + wave * 4096;
#pragma unroll
  for (int t = 0; t < 16; ++t) {
    int pcb = t * 2 + (col >> 3);
#pragma unroll
    for (int i = 0; i < 4; ++i) {
      int r = quad * 4 + i;
      P[r * 256 + ((pcb ^ (r & 7)) << 3) + (col & 7)] = f2bf(sc[t][i] * inv[i]);
    }
  }

  f32x4 o[4];
#pragma unroll
  for (int nt = 0; nt < 4; ++nt) o[nt] = (f32x4){0.f, 0.f, 0.f, 0.f};
  const uint16_t* Vt = lds + 16384;
#pragma unroll
  for (int c = 0; c < 8; ++c) {
    int pc = c * 4 + quad;
    bf16x8 ap = *(const bf16x8*)(P + col * 256 + ((pc ^ (col & 7)) << 3));
#pragma unroll
    for (int nt = 0; nt < 4; ++nt) {
      int d = nt * 16 + col;
      bf16x8 bv = *(const bf16x8*)(Vt + d * 256 + ((pc ^ (d & 7)) << 3));
      o[nt] = __builtin_amdgcn_mfma_f32_16x16x32_bf16(ap, bv, o[nt], 0, 0, 0);
    }
  }

#pragma unroll
  for (int nt = 0; nt < 4; ++nt) {
#pragma unroll
    for (int r = 0; r < 4; ++r) {
      int grow = row0 + qc * 64 + wave * 16 + quad * 4 + r;
      int gcol = h * 64 + nt * 16 + col;
      out[(size_t)grow * 1024 + gcol] = f2bf(o[nt][r]);
    }
  }
}

// ---------------------------------------------------------------------------
extern "C" void kernel_launch(void* const* d_in, const int* in_sizes, int n_in,
                              void* d_out, int out_size, void* d_ws, size_t ws_size,
                              hipStream_t stream) {
  const float* x        = (const float*)d_in[0];
  const float* time_emb = (const float*)d_in[1];
  const float* norm1_w  = (const float*)d_in[2];
  const float* norm2_w  = (const float*)d_in[3];
  const float* qkv_w    = (const float*)d_in[4];
  const float* out_w    = (const float*)d_in[5];
  const float* w1       = (const float*)d_in[6];
  const float* w2       = (const float*)d_in[7];
  const float* w3       = (const float*)d_in[8];
  const float* mod_w    = (const float*)d_in[9];
  const float* mod_b    = (const float*)d_in[10];
  float* out = (float*)d_out;

  char* ws = (char*)d_ws;
  float*    mod    = (float*)(ws);
  uint16_t* wqkv_t = (uint16_t*)(ws + 98304);
  uint16_t* wout_t = (uint16_t*)(ws + 6389760);
  uint16_t* w1t    = (uint16_t*)(ws + 8486912);
  uint16_t* w2t    = (uint16_t*)(ws + 14123008);
  uint16_t* w3t    = (uint16_t*)(ws + 19759104);
  uint16_t* hbuf   = (uint16_t*)(ws + 25395200);
  uint16_t* qkvb   = (uint16_t*)(ws + 58949632);
  uint16_t* hid    = qkvb;

  dim3 blk(256);
  transpose_cast<<<dim3(3072 / 32, 1024 / 32), blk, 0, stream>>>(qkv_w, wqkv_t, 1024, 3072);
  transpose_cast<<<dim3(1024 / 32, 1024 / 32), blk, 0, stream>>>(out_w, wout_t, 1024, 1024);
  transpose_cast<<<dim3(2752 / 32, 1024 / 32), blk, 0, stream>>>(w1, w1t, 1024, 2752);
  transpose_cast<<<dim3(2752 / 32, 1024 / 32), blk, 0, stream>>>(w2, w2t, 1024, 2752);
  transpose_cast<<<dim3(1024 / 32, 2752 / 32), blk, 0, stream>>>(w3, w3t, 2752, 1024);

  mod_kernel<<<24, 1024, 0, stream>>>(time_emb, mod_w, mod_b, mod);

  norm_kernel<<<16384, blk, 0, stream>>>(x, norm1_w, mod, 0, 1024, hbuf);

  // qkv = h @ qkv_w   (M=16384,N=3072,K=1024)  tiles_m=128, tiles_n=24
  gemm_bt<0><<<128 * 24, blk, 0, stream>>>(hbuf, wqkv_t, 16384, 3072, 1024,
                                           qkvb, nullptr, nullptr, nullptr, nullptr);
  attn_kernel<<<4096, blk, 0, stream>>>(qkvb, hbuf);

  // x1 = x + gate1 * (attn @ out_w) -> d_out (fp32)
  gemm_bt<1><<<128 * 8, blk, 0, stream>>>(hbuf, wout_t, 16384, 1024, 1024,
                                          nullptr, x, mod, nullptr, out);
  // h2 = rmsnorm(x1)*(1+scale2)+shift2
  norm_kernel<<<16384, blk, 0, stream>>>(out, norm2_w, mod, 3072, 4096, hbuf);

  // h1 = silu(h2 @ w1)  (N=2752)
  gemm_bt<2><<<128 * 22, blk, 0, stream>>>(hbuf, w1t, 16384, 2752, 1024,
                                           hid, nullptr, nullptr, nullptr, nullptr);
  // hid = h1 * (h2 @ w2)   (in place over h1)
  gemm_bt<3><<<128 * 22, blk, 0, stream>>>(hbuf, w2t, 16384, 2752, 1024,
                                           hid, nullptr, nullptr, hid, nullptr);
  // out = x1 + gate2 * (hid @ w3)   (fp32 RMW, K=2752)
  gemm_bt<4><<<128 * 8, blk, 0, stream>>>(hid, w3t, 16384, 1024, 2752,
                                          nullptr, nullptr, mod, nullptr, out);
}

// Round 7
// 834.856 us; speedup vs baseline: 1.7091x; 1.0916x over previous
//
#include <hip/hip_runtime.h>
#include <stdint.h>

// ---------------------------------------------------------------------------
// TransformerBlock bf16 MFMA. OUTPUT FP32.
// Round 7: BK=64 double-buffered GEMM K-loop (32 MFMA per barrier drain, 2x
// in-flight cover, half the drains vs round 6). 128x128 tile, 64 acc VGPRs
// (proven sweet spot), XCD remap kept. LDS 64 KB -> 2 blocks/CU.
// ---------------------------------------------------------------------------

using bf16x8 = __attribute__((ext_vector_type(8))) short;
using f32x4  = __attribute__((ext_vector_type(4))) float;

typedef __attribute__((address_space(3))) uint16_t lds16_t;

__device__ __forceinline__ float bf2f(uint16_t h) {
  union { uint32_t u; float f; } v; v.u = ((uint32_t)h) << 16; return v.f;
}
__device__ __forceinline__ uint16_t f2bf(float f) {
  union { float f; uint32_t u; } v; v.f = f;
  uint32_t r = v.u + 0x7FFFu + ((v.u >> 16) & 1u);
  return (uint16_t)(r >> 16);
}
__device__ __forceinline__ float silu(float x) { return x / (1.0f + __expf(-x)); }

__device__ __forceinline__ void gload16(const uint16_t* g, lds16_t* l) {
  __builtin_amdgcn_global_load_lds(
      (const __attribute__((address_space(1))) void*)g,
      (__attribute__((address_space(3))) void*)l, 16, 0, 0);
}

// ---------------------------------------------------------------------------
// Transpose-cast: wt[n][k] = (bf16) w[k][n].  w is (K,N) fp32 row-major.
// ---------------------------------------------------------------------------
__global__ __launch_bounds__(256)
void transpose_cast(const float* __restrict__ w, uint16_t* __restrict__ wt,
                    int K, int N) {
  __shared__ float tile[32][33];
  int n0 = blockIdx.x * 32, k0 = blockIdx.y * 32;
  int tx = threadIdx.x & 31, ty = threadIdx.x >> 5;
#pragma unroll
  for (int it = 0; it < 4; ++it) {
    int r = ty + it * 8;
    tile[r][tx] = w[(k0 + r) * N + n0 + tx];
  }
  __syncthreads();
#pragma unroll
  for (int it = 0; it < 4; ++it) {
    int r = ty + it * 8;
    wt[(n0 + r) * K + k0 + tx] = f2bf(tile[tx][r]);
  }
}

// ---------------------------------------------------------------------------
// mod = silu(time_emb) @ mod_w + mod_b      (4 x 6144, K=1024)
// ---------------------------------------------------------------------------
__global__ __launch_bounds__(1024)
void mod_kernel(const float* __restrict__ te, const float* __restrict__ mw,
                const float* __restrict__ mb, float* __restrict__ mod) {
  __shared__ float ste[4096];
  __shared__ float red[4][4][256];
  int tid = threadIdx.x;
  for (int i = tid; i < 4096; i += 1024) { float v = te[i]; ste[i] = silu(v); }
  __syncthreads();
  int kslice = tid >> 8, cl = tid & 255;
  int col = blockIdx.x * 256 + cl;
  float acc[4] = {0.f, 0.f, 0.f, 0.f};
  for (int kk = 0; kk < 256; ++kk) {
    int k = kslice * 256 + kk;
    float wv = mw[k * 6144 + col];
#pragma unroll
    for (int b = 0; b < 4; ++b) acc[b] += ste[b * 1024 + k] * wv;
  }
#pragma unroll
  for (int b = 0; b < 4; ++b) red[kslice][b][cl] = acc[b];
  __syncthreads();
  if (kslice == 0) {
#pragma unroll
    for (int b = 0; b < 4; ++b)
      mod[b * 6144 + col] =
          red[0][b][cl] + red[1][b][cl] + red[2][b][cl] + red[3][b][cl] + mb[col];
  }
}

// ---------------------------------------------------------------------------
// RMSNorm + modulation -> bf16.  One block per row.
// ---------------------------------------------------------------------------
__global__ __launch_bounds__(256)
void norm_kernel(const float* __restrict__ xf,
                 const float* __restrict__ w, const float* __restrict__ mod,
                 int shift_off, int scale_off, uint16_t* __restrict__ out) {
  int row = blockIdx.x;
  int b = row >> 12;
  int tid = threadIdx.x;
  float4 t = *(const float4*)(xf + (size_t)row * 1024 + tid * 4);
  float v[4] = {t.x, t.y, t.z, t.w};
  float ss = v[0] * v[0] + v[1] * v[1] + v[2] * v[2] + v[3] * v[3];
#pragma unroll
  for (int off = 1; off < 64; off <<= 1) ss += __shfl_xor(ss, off);
  __shared__ float red[4];
  if ((tid & 63) == 0) red[tid >> 6] = ss;
  __syncthreads();
  float tot = red[0] + red[1] + red[2] + red[3];
  float rinv = rsqrtf(tot * (1.0f / 1024.0f) + 1e-6f);
  const float* mrow = mod + b * 6144;
  uint16_t o[4];
#pragma unroll
  for (int c = 0; c < 4; ++c) {
    int col = tid * 4 + c;
    float hv = v[c] * rinv * w[col] * (1.0f + mrow[scale_off + col]) + mrow[shift_off + col];
    o[c] = f2bf(hv);
  }
  uint2 pk;
  pk.x = (uint32_t)o[0] | ((uint32_t)o[1] << 16);
  pk.y = (uint32_t)o[2] | ((uint32_t)o[3] << 16);
  *(uint2*)(out + (size_t)row * 1024 + tid * 4) = pk;
}

// ---------------------------------------------------------------------------
// GEMM: C(M,N) = A(M,K)bf16 @ Bt(N,K)bf16, 128x128 tile, BK=64, 4 waves 2x2,
// wave = 64x64 via 4x4 mfma_16x16x32_bf16 over two K-halves (32 MFMA/barrier).
// Double-buffered LDS (2 x 32 KB). LDS rows = 64 elems (128 B, bank-uniform).
// XOR-8 swizzle: phys 16B-chunk p of row r holds logical chunk p^(r&7);
// staging source applies same swizzle (DMA contiguous, global coalesced).
// XCD remap: xcd = bid&7, tm-major per XCD. Requires (M/128) % 8 == 0.
// MODE: 0 store bf16 | 1 x+gate1*C -> fp32 | 2 silu bf16 | 3 h1*C bf16
//       4 xio += gate2*C (fp32 RMW)
// ---------------------------------------------------------------------------
template <int MODE>
__global__ __launch_bounds__(256)
void gemm_bt(const uint16_t* __restrict__ A, const uint16_t* __restrict__ Bt,
             int M, int N, int K,
             uint16_t* __restrict__ obf,
             const float* __restrict__ xin, const float* __restrict__ mod,
             const uint16_t* __restrict__ h1, float* __restrict__ xio) {
  __shared__ uint16_t As[2][128 * 64];   // 2 x 16 KB
  __shared__ uint16_t Bs[2][128 * 64];
  const int tiles_n = (N + 127) >> 7;
  const int xcd = blockIdx.x & 7;
  const int slot = blockIdx.x >> 3;
  const int tm = (slot / tiles_n) * 8 + xcd;
  const int tn = slot % tiles_n;
  const int m0 = tm * 128, n0 = tn * 128;
  const int tid = threadIdx.x;
  const int wave = tid >> 6, lane = tid & 63;
  const int wm = (wave & 1) * 64, wn = (wave >> 1) * 64;
  const int col = lane & 15, quad = lane >> 4;

  // staging: thread t covers (row = 32*r + (t>>3), phys chunk = t&7), r=0..3
  // source logical chunk = (t&7) ^ (row&7)
  const int srow = tid >> 3, sphys = tid & 7;
  const int slog = ((sphys ^ (srow & 7)) << 3);      // elem offset in row
  const uint16_t* Ag[4]; const uint16_t* Bg[4];
#pragma unroll
  for (int r = 0; r < 4; ++r) {
    Ag[r] = A + (size_t)(m0 + 32 * r + srow) * K + slog;
    int br = n0 + 32 * r + srow; if (br >= N) br = N - 1;
    Bg[r] = Bt + (size_t)br * K + slog;
  }
  lds16_t* Alb[2]; lds16_t* Blb[2];
#pragma unroll
  for (int b = 0; b < 2; ++b) {
    Alb[b] = (lds16_t*)As[b] + tid * 8;   // + r*2048 per round
    Blb[b] = (lds16_t*)Bs[b] + tid * 8;
  }

  f32x4 acc[4][4];
#pragma unroll
  for (int i = 0; i < 4; ++i)
#pragma unroll
    for (int j = 0; j < 4; ++j) acc[i][j] = (f32x4){0.f, 0.f, 0.f, 0.f};

  const int c7 = col & 7;
  const int swzk[2] = {((quad ^ c7) << 3), (((4 + quad) ^ c7) << 3)};

  // prologue: stage tile 0 into buffer 0
#pragma unroll
  for (int r = 0; r < 4; ++r) gload16(Ag[r], Alb[0] + r * 2048);
#pragma unroll
  for (int r = 0; r < 4; ++r) gload16(Bg[r], Blb[0] + r * 2048);

  for (int k0 = 0; k0 < K; k0 += 64) {
    const int cur = (k0 >> 6) & 1;
    __syncthreads();     // buffer `cur` staged; prev iter's reads done
    if (k0 + 64 < K) {   // stage tile k+1 into other buffer (in flight
      const int kn = k0 + 64;            // through this iteration's compute)
#pragma unroll
      for (int r = 0; r < 4; ++r) gload16(Ag[r] + kn, Alb[cur ^ 1] + r * 2048);
#pragma unroll
      for (int r = 0; r < 4; ++r) gload16(Bg[r] + kn, Blb[cur ^ 1] + r * 2048);
    }
    const uint16_t* Ab = As[cur];
    const uint16_t* Bb = Bs[cur];
#pragma unroll
    for (int ks = 0; ks < 2; ++ks) {
      const int swz = swzk[ks];
      bf16x8 af[4], bfr[4];
#pragma unroll
      for (int i = 0; i < 4; ++i)
        af[i] = *(const bf16x8*)(Ab + (wm + i * 16 + col) * 64 + swz);
#pragma unroll
      for (int j = 0; j < 4; ++j)
        bfr[j] = *(const bf16x8*)(Bb + (wn + j * 16 + col) * 64 + swz);
#pragma unroll
      for (int i = 0; i < 4; ++i)
#pragma unroll
        for (int j = 0; j < 4; ++j)
          acc[i][j] = __builtin_amdgcn_mfma_f32_16x16x32_bf16(af[i], bfr[j], acc[i][j], 0, 0, 0);
    }
  }

#pragma unroll
  for (int i = 0; i < 4; ++i) {
#pragma unroll
    for (int j = 0; j < 4; ++j) {
#pragma unroll
      for (int r = 0; r < 4; ++r) {
        int row = m0 + wm + i * 16 + quad * 4 + r;
        int cn = n0 + wn + j * 16 + col;
        if (cn >= N) continue;
        float c = acc[i][j][r];
        if (MODE == 0) {
          obf[(size_t)row * N + cn] = f2bf(c);
        } else if (MODE == 1) {
          int b = row >> 12;
          size_t idx = (size_t)row * 1024 + cn;
          float g = mod[b * 6144 + 2048 + cn];
          xio[idx] = xin[idx] + g * c;
        } else if (MODE == 2) {
          obf[(size_t)row * N + cn] = f2bf(silu(c));
        } else if (MODE == 3) {
          size_t idx = (size_t)row * N + cn;
          obf[idx] = f2bf(bf2f(h1[idx]) * c);
        } else {  // MODE 4
          int b = row >> 12;
          size_t idx = (size_t)row * 1024 + cn;
          float g = mod[b * 6144 + 5120 + cn];
          xio[idx] = xio[idx] + g * c;
        }
      }
    }
  }
}

// ---------------------------------------------------------------------------
// Fused attention (unchanged, verified).
// ---------------------------------------------------------------------------
__global__ __launch_bounds__(256)
void attn_kernel(const uint16_t* __restrict__ qkv, uint16_t* __restrict__ out) {
  __shared__ uint16_t lds[32768];
  const int tid = threadIdx.x;
  const int bid = blockIdx.x;
  const int slice = bid >> 2, qc = bid & 3;
  const int bt = slice >> 4, h = slice & 15;
  const int row0 = bt * 256;
  const int wave = tid >> 6, lane = tid & 63;
  const int col = lane & 15, quad = lane >> 4;

  {
    int kr = tid;
    const uint16_t* kp = qkv + (size_t)(row0 + kr) * 3072 + 1024 + h * 64;
    uint16_t* ks = lds + kr * 64;
#pragma unroll
    for (int kc = 0; kc < 8; ++kc) {
      uint4 v = *(const uint4*)(kp + kc * 8);
      *(uint4*)(ks + ((kc ^ (kr & 7)) << 3)) = v;
    }
  }
  {
    int p = tid & 127, dh = tid >> 7;
    const uint16_t* vp0 = qkv + (size_t)(row0 + 2 * p) * 3072 + 2048 + h * 64 + dh * 32;
    const uint16_t* vp1 = vp0 + 3072;
    uint16_t r0[32], r1[32];
#pragma unroll
    for (int i = 0; i < 4; ++i) {
      *(uint4*)(r0 + i * 8) = *(const uint4*)(vp0 + i * 8);
      *(uint4*)(r1 + i * 8) = *(const uint4*)(vp1 + i * 8);
    }
    uint32_t* vt = (uint32_t*)(lds + 16384);
    int krc = p >> 2;
#pragma unroll
    for (int i = 0; i < 32; ++i) {
      int d = dh * 32 + i;
      uint32_t val = (uint32_t)r0[i] | ((uint32_t)r1[i] << 16);
      vt[d * 128 + ((krc ^ (d & 7)) << 2) + (p & 3)] = val;
    }
  }
  __syncthreads();

  const int qrow = qc * 64 + wave * 16 + col;
  const uint16_t* qp = qkv + (size_t)(row0 + qrow) * 3072 + h * 64;
  bf16x8 aq0 = *(const bf16x8*)(qp + quad * 8);
  bf16x8 aq1 = *(const bf16x8*)(qp + 32 + quad * 8);

  f32x4 sc[16];
#pragma unroll
  for (int t = 0; t < 16; ++t) {
    int n = t * 16 + col;
    const uint16_t* kb = lds + n * 64;
    bf16x8 b0 = *(const bf16x8*)(kb + ((quad ^ (n & 7)) << 3));
    bf16x8 b1 = *(const bf16x8*)(kb + (((4 + quad) ^ (n & 7)) << 3));
    f32x4 s = (f32x4){0.f, 0.f, 0.f, 0.f};
    s = __builtin_amdgcn_mfma_f32_16x16x32_bf16(aq0, b0, s, 0, 0, 0);
    s = __builtin_amdgcn_mfma_f32_16x16x32_bf16(aq1, b1, s, 0, 0, 0);
    sc[t] = s;
  }

  const float scale = 0.125f;
  float inv[4];
#pragma unroll
  for (int i = 0; i < 4; ++i) {
    float m = -1e30f;
#pragma unroll
    for (int t = 0; t < 16; ++t) m = fmaxf(m, sc[t][i]);
    m = fmaxf(m, __shfl_xor(m, 1));
    m = fmaxf(m, __shfl_xor(m, 2));
    m = fmaxf(m, __shfl_xor(m, 4));
    m = fmaxf(m, __shfl_xor(m, 8));
    m *= scale;
    float sum = 0.f;
#pragma unroll
    for (int t = 0; t < 16; ++t) {
      float p = __expf(sc[t][i] * scale - m);
      sc[t][i] = p;
      sum += p;
    }
    sum += __shfl_xor(sum, 1);
    sum += __shfl_xor(sum, 2);
    sum += __shfl_xor(sum, 4);
    sum += __shfl_xor(sum, 8);
    inv[i] = 1.0f / sum;
  }
  __syncthreads();

  uint16_t* P = lds + wave * 4096;
#pragma unroll
  for (int t = 0; t < 16; ++t) {
    int pcb = t * 2 + (col >> 3);
#pragma unroll
    for (int i = 0; i < 4; ++i) {
      int r = quad * 4 + i;
      P[r * 256 + ((pcb ^ (r & 7)) << 3) + (col & 7)] = f2bf(sc[t][i] * inv[i]);
    }
  }

  f32x4 o[4];
#pragma unroll
  for (int nt = 0; nt < 4; ++nt) o[nt] = (f32x4){0.f, 0.f, 0.f, 0.f};
  const uint16_t* Vt = lds + 16384;
#pragma unroll
  for (int c = 0; c < 8; ++c) {
    int pc = c * 4 + quad;
    bf16x8 ap = *(const bf16x8*)(P + col * 256 + ((pc ^ (col & 7)) << 3));
#pragma unroll
    for (int nt = 0; nt < 4; ++nt) {
      int d = nt * 16 + col;
      bf16x8 bv = *(const bf16x8*)(Vt + d * 256 + ((pc ^ (d & 7)) << 3));
      o[nt] = __builtin_amdgcn_mfma_f32_16x16x32_bf16(ap, bv, o[nt], 0, 0, 0);
    }
  }

#pragma unroll
  for (int nt = 0; nt < 4; ++nt) {
#pragma unroll
    for (int r = 0; r < 4; ++r) {
      int grow = row0 + qc * 64 + wave * 16 + quad * 4 + r;
      int gcol = h * 64 + nt * 16 + col;
      out[(size_t)grow * 1024 + gcol] = f2bf(o[nt][r]);
    }
  }
}

// ---------------------------------------------------------------------------
extern "C" void kernel_launch(void* const* d_in, const int* in_sizes, int n_in,
                              void* d_out, int out_size, void* d_ws, size_t ws_size,
                              hipStream_t stream) {
  const float* x        = (const float*)d_in[0];
  const float* time_emb = (const float*)d_in[1];
  const float* norm1_w  = (const float*)d_in[2];
  const float* norm2_w  = (const float*)d_in[3];
  const float* qkv_w    = (const float*)d_in[4];
  const float* out_w    = (const float*)d_in[5];
  const float* w1       = (const float*)d_in[6];
  const float* w2       = (const float*)d_in[7];
  const float* w3       = (const float*)d_in[8];
  const float* mod_w    = (const float*)d_in[9];
  const float* mod_b    = (const float*)d_in[10];
  float* out = (float*)d_out;

  char* ws = (char*)d_ws;
  float*    mod    = (float*)(ws);
  uint16_t* wqkv_t = (uint16_t*)(ws + 98304);
  uint16_t* wout_t = (uint16_t*)(ws + 6389760);
  uint16_t* w1t    = (uint16_t*)(ws + 8486912);
  uint16_t* w2t    = (uint16_t*)(ws + 14123008);
  uint16_t* w3t    = (uint16_t*)(ws + 19759104);
  uint16_t* hbuf   = (uint16_t*)(ws + 25395200);
  uint16_t* qkvb   = (uint16_t*)(ws + 58949632);
  uint16_t* hid    = qkvb;

  dim3 blk(256);
  transpose_cast<<<dim3(3072 / 32, 1024 / 32), blk, 0, stream>>>(qkv_w, wqkv_t, 1024, 3072);
  transpose_cast<<<dim3(1024 / 32, 1024 / 32), blk, 0, stream>>>(out_w, wout_t, 1024, 1024);
  transpose_cast<<<dim3(2752 / 32, 1024 / 32), blk, 0, stream>>>(w1, w1t, 1024, 2752);
  transpose_cast<<<dim3(2752 / 32, 1024 / 32), blk, 0, stream>>>(w2, w2t, 1024, 2752);
  transpose_cast<<<dim3(1024 / 32, 2752 / 32), blk, 0, stream>>>(w3, w3t, 2752, 1024);

  mod_kernel<<<24, 1024, 0, stream>>>(time_emb, mod_w, mod_b, mod);

  norm_kernel<<<16384, blk, 0, stream>>>(x, norm1_w, mod, 0, 1024, hbuf);

  // qkv = h @ qkv_w   (M=16384,N=3072,K=1024)
  gemm_bt<0><<<128 * 24, blk, 0, stream>>>(hbuf, wqkv_t, 16384, 3072, 1024,
                                           qkvb, nullptr, nullptr, nullptr, nullptr);
  attn_kernel<<<4096, blk, 0, stream>>>(qkvb, hbuf);

  // x1 = x + gate1 * (attn @ out_w) -> d_out (fp32)
  gemm_bt<1><<<128 * 8, blk, 0, stream>>>(hbuf, wout_t, 16384, 1024, 1024,
                                          nullptr, x, mod, nullptr, out);
  // h2 = rmsnorm(x1)*(1+scale2)+shift2
  norm_kernel<<<16384, blk, 0, stream>>>(out, norm2_w, mod, 3072, 4096, hbuf);

  // h1 = silu(h2 @ w1)  (N=2752)
  gemm_bt<2><<<128 * 22, blk, 0, stream>>>(hbuf, w1t, 16384, 2752, 1024,
                                           hid, nullptr, nullptr, nullptr, nullptr);
  // hid = h1 * (h2 @ w2)   (in place over h1)
  gemm_bt<3><<<128 * 22, blk, 0, stream>>>(hbuf, w2t, 16384, 2752, 1024,
                                           hid, nullptr, nullptr, hid, nullptr);
  // out = x1 + gate2 * (hid @ w3)   (fp32 RMW, K=2752)
  gemm_bt<4><<<128 * 8, blk, 0, stream>>>(hid, w3t, 16384, 1024, 2752,
                                          nullptr, nullptr, mod, nullptr, out);
}